// Round 6
// baseline (1080.980 us; speedup 1.0000x reference)
//
#include <hip/hip_runtime.h>

#define K_TOP 300
#define NCLS  80
#define CAP   4096       // per-batch candidate capacity (global buffer + LDS)
#define NBUCK 4096
#define NB    256
#define NF4   20000      // float4 per batch (80000 floats)
#define TOTF4 (NB * NF4) // 5,120,000 float4 total
#define GTHR  2.2f       // static collect threshold; rank-300 sits at z~2.67

typedef unsigned int       u32;
typedef unsigned long long u64;

__device__ __forceinline__ u32 order_f32(float f) {
    u32 u = __float_as_uint(f);
    return u ^ ((u >> 31) ? 0xFFFFFFFFu : 0x80000000u);
}
__device__ __forceinline__ float unorder_f32(u32 u) {
    u32 v = (u & 0x80000000u) ? (u ^ 0x80000000u) : ~u;
    return __uint_as_float(v);
}

// ---------------- kernel A: streaming threshold-collect (no LDS) ----------------
__device__ __forceinline__ void push(u32* __restrict__ gcnt, u64* __restrict__ gbuf,
                                     int b, int idx, float v) {
    u32 o = order_f32(v);
    u32 pos = atomicAdd(&gcnt[b], 1u);
    if (pos < CAP)
        gbuf[(size_t)b * CAP + pos] = ((u64)o << 32) | (u64)(0xFFFFFFFFu - (u32)idx);
}

__global__ __launch_bounds__(256) void collect_kernel(
    const float* __restrict__ logits,
    u32* __restrict__ gcnt,
    u64* __restrict__ gbuf)
{
    const int stride = gridDim.x * 256;
    int i = blockIdx.x * 256 + threadIdx.x;
    if (i >= TOTF4) return;
    const float4* __restrict__ L4 = (const float4*)logits;
    float4 v = L4[i];
    while (true) {
        const int nx = i + stride;
        const bool more = (nx < TOTF4);
        float4 nv;
        if (more) nv = L4[nx];          // prefetch next iteration's load
        const int b    = i / NF4;       // magic-mul
        const int base = (i - b * NF4) * 4;
        if (v.x >= GTHR) push(gcnt, gbuf, b, base + 0, v.x);
        if (v.y >= GTHR) push(gcnt, gbuf, b, base + 1, v.y);
        if (v.z >= GTHR) push(gcnt, gbuf, b, base + 2, v.z);
        if (v.w >= GTHR) push(gcnt, gbuf, b, base + 3, v.w);
        if (!more) break;
        v = nv; i = nx;
    }
}

// ---------------- kernel B: per-batch select / rank / write ----------------

// suffix-scan hist counts -> exclusive-suffix starts (into hist AND cur),
// *s_B = max bucket with suffix(>=bk) >= K_TOP. Caller barriers before/after.
__device__ __forceinline__ void scan_and_find_B(u32* hist, u32* cur,
                                                u32* csum, u32* csum2,
                                                int* s_B, int t) {
    csum[t] = hist[4*t] + hist[4*t+1] + hist[4*t+2] + hist[4*t+3];
    __syncthreads();
    if (t < 64) {
        u32 s = 0;
        for (int u = 0; u < 16; ++u) s += csum[16*t + u];
        csum2[t] = s;
    }
    __syncthreads();
    if (t == 0) {     // exclusive suffix over the 64 supergroup sums
        u32 run = 0;
        for (int s = 63; s >= 0; --s) { u32 v = csum2[s]; csum2[s] = run; run += v; }
    }
    __syncthreads();
    {
        u32 ex = csum2[t >> 4];
        for (int g2 = (t | 15); g2 > t; --g2) ex += csum[g2];
        u32 h0 = hist[4*t], h1 = hist[4*t+1], h2 = hist[4*t+2], h3 = hist[4*t+3];
        u32 st3 = ex;
        u32 st2 = st3 + h3;
        u32 st1 = st2 + h2;
        u32 st0 = st1 + h1;
        int bl = -1;   // suffix(>=bk) non-increasing: first hit from top is max
        if      (st3 + h3 >= K_TOP) bl = 4*t + 3;
        else if (st2 + h2 >= K_TOP) bl = 4*t + 2;
        else if (st1 + h1 >= K_TOP) bl = 4*t + 1;
        else if (st0 + h0 >= K_TOP) bl = 4*t + 0;
        if (bl >= 0) atomicMax(s_B, bl);
        hist[4*t] = st0; hist[4*t+1] = st1; hist[4*t+2] = st2; hist[4*t+3] = st3;
        cur [4*t] = st0; cur [4*t+1] = st1; cur [4*t+2] = st2; cur [4*t+3] = st3;
    }
}

__device__ __forceinline__ void write_row(float* __restrict__ out, int b, int rank,
                                          u64 key, const float4* __restrict__ BX,
                                          float sx, float sy) {
    u32 o   = (u32)(key >> 32);
    u32 idx = ~((u32)key);
    float logit = unorder_f32(o);
    float score = 1.0f / (1.0f + expf(-logit));
    int label = (int)(idx % NCLS);
    int q     = (int)(idx / NCLS);
    float4 bx = BX[q];
    float* po = out + ((size_t)b * K_TOP + rank) * 6;
    po[0] = (float)label;
    po[1] = score;
    po[2] = (bx.x - 0.5f * bx.z) * sx;
    po[3] = (bx.y - 0.5f * bx.w) * sy;
    po[4] = bx.z * sx;
    po[5] = bx.w * sy;
}

// rank within own bucket segment (cand bucket-grouped); write top-300
__device__ __forceinline__ void rank_and_write(const u64* cand, const u32* hist,
                                               const u32* cur, u32 B, int t, int b,
                                               const float4* BX, float sx, float sy,
                                               float* out) {
    int total = (int)cur[B]; if (total > CAP) total = CAP;
    for (int i = t; i < total; i += 1024) {
        u64 key = cand[i];
        int bk   = (int)(key >> 52);
        int segS = (int)hist[bk];
        int segE = (int)cur[bk]; if (segE > CAP) segE = CAP;
        int r = segS;
        for (int j = segS; j < segE; ++j)
            r += (cand[j] > key) ? 1 : 0;
        if (r < K_TOP)
            write_row(out, b, r, key, BX, sx, sy);
    }
}

// fallback collect (bucket-filtered, cursor-scattered)
__device__ __forceinline__ void collect1(u32 o, int idx, u32 B,
                                         u64* cand, u32* cur) {
    u32 bk = o >> 20;
    if (bk >= B) {
        u32 pos = atomicAdd(&cur[bk], 1u);
        if (pos < CAP)
            cand[pos] = ((u64)o << 32) | (u64)(0xFFFFFFFFu - (u32)idx);
    }
}

__global__ __launch_bounds__(1024) void select_kernel(
    const float* __restrict__ logits,
    const float* __restrict__ boxes,
    const int*   __restrict__ osz,
    const u32*   __restrict__ gcnt,
    const u64*   __restrict__ gbuf,
    float*       __restrict__ out,
    int use_ws)
{
    __shared__ u32 hist[NBUCK];    // counts -> segment starts
    __shared__ u32 cur[NBUCK];     // fill cursors (ends after scatter)
    __shared__ u64 cand[CAP];      // bucket-grouped candidates (32 KB)
    __shared__ u32 csum[1024];
    __shared__ u32 csum2[64];
    __shared__ int s_B;

    const int b = blockIdx.x;
    const int t = threadIdx.x;
    const float4* L4 = (const float4*)(logits + (size_t)b * (NF4 * 4));
    const u64* gb = gbuf + (size_t)b * CAP;

    for (int i = t; i < NBUCK; i += 1024) hist[i] = 0;
    if (t == 0) s_B = -1;
    __syncthreads();

    const u32 BUCKET_G = order_f32(GTHR) >> 20;
    const int rawcnt = use_ws ? (int)gcnt[b] : -1;
    bool fast = use_ws && (rawcnt >= K_TOP) && (rawcnt <= CAP);

    const float sx = (float)osz[1];   // scale = [W, H, W, H]
    const float sy = (float)osz[0];
    const float4* BX = (const float4*)(boxes + (size_t)b * 4000);

    if (fast) {
        // histogram ONLY candidates; suffix counts exact for bk > BUCKET_G
        for (int i = t; i < rawcnt; i += 1024)
            atomicAdd(&hist[(u32)(gb[i] >> 52)], 1u);
        __syncthreads();
        scan_and_find_B(hist, cur, csum, csum2, &s_B, t);
        __syncthreads();
        fast = (s_B > (int)BUCKET_G);   // B valid only if above collect bucket
    }

    if (fast) {
        const u32 B = (u32)s_B;
        for (int i = t; i < rawcnt; i += 1024) {   // scatter bucket-grouped
            u64 k = gb[i];
            u32 pos = atomicAdd(&cur[(u32)(k >> 52)], 1u);
            if (pos < CAP) cand[pos] = k;
        }
        __syncthreads();
        rank_and_write(cand, hist, cur, B, t, b, BX, sx, sy, out);
    } else {
        // ---- fallback (degenerate data / no ws): full two-pass, always correct ----
        __syncthreads();
        for (int i = t; i < NBUCK; i += 1024) hist[i] = 0;
        if (t == 0) s_B = -1;
        __syncthreads();
        for (int i = t; i < NF4; i += 1024) {
            float4 v = L4[i];
            atomicAdd(&hist[order_f32(v.x) >> 20], 1u);
            atomicAdd(&hist[order_f32(v.y) >> 20], 1u);
            atomicAdd(&hist[order_f32(v.z) >> 20], 1u);
            atomicAdd(&hist[order_f32(v.w) >> 20], 1u);
        }
        __syncthreads();
        scan_and_find_B(hist, cur, csum, csum2, &s_B, t);
        __syncthreads();
        const u32 B = (u32)s_B;
        for (int i = t; i < NF4; i += 1024) {
            float4 v = L4[i];
            collect1(order_f32(v.x), 4*i + 0, B, cand, cur);
            collect1(order_f32(v.y), 4*i + 1, B, cand, cur);
            collect1(order_f32(v.z), 4*i + 2, B, cand, cur);
            collect1(order_f32(v.w), 4*i + 3, B, cand, cur);
        }
        __syncthreads();
        rank_and_write(cand, hist, cur, B, t, b, BX, sx, sy, out);
    }
}

extern "C" void kernel_launch(void* const* d_in, const int* in_sizes, int n_in,
                              void* d_out, int out_size, void* d_ws, size_t ws_size,
                              hipStream_t stream) {
    const float* logits = (const float*)d_in[0];
    const float* boxes  = (const float*)d_in[1];
    const int*   osz    = (const int*)d_in[2];
    float* out = (float*)d_out;

    const size_t need = 4096 + (size_t)NB * CAP * sizeof(u64);
    const int use_ws = (ws_size >= need) ? 1 : 0;
    u32* gcnt = (u32*)d_ws;
    u64* gbuf = (u64*)((char*)d_ws + 4096);

    if (use_ws) {
        hipMemsetAsync(d_ws, 0, NB * sizeof(u32), stream);
        collect_kernel<<<dim3(2048), dim3(256), 0, stream>>>(logits, gcnt, gbuf);
    }
    select_kernel<<<dim3(NB), dim3(1024), 0, stream>>>(logits, boxes, osz,
                                                       gcnt, gbuf, out, use_ws);
}

// Round 7
// 50.026 us; speedup vs baseline: 21.6083x; 21.6083x over previous
//
#include <hip/hip_runtime.h>

#define K_TOP  300
#define NCLS   80
#define CAP    4096      // per-batch candidate capacity in gbuf
#define NBUCK  4096
#define NB     256
#define NF4    20000     // float4 per batch (80000 floats)
#define GTHR   2.2f      // static collect threshold; rank-300 sits at z~2.67
#define BPB    10        // collect blocks per batch
#define CHUNK  2048      // float4 per collect block (last chunk ragged: 1568)
#define LDSCAP 768       // per-block LDS winner capacity (expect ~110)

typedef unsigned int       u32;
typedef unsigned long long u64;

__device__ __forceinline__ u32 order_f32(float f) {
    u32 u = __float_as_uint(f);
    return u ^ ((u >> 31) ? 0xFFFFFFFFu : 0x80000000u);
}
__device__ __forceinline__ float unorder_f32(u32 u) {
    u32 v = (u & 0x80000000u) ? (u ^ 0x80000000u) : ~u;
    return __uint_as_float(v);
}

// ---------------- kernel A: chunked threshold-collect, LDS-staged ----------------
__device__ __forceinline__ void lpush(u64* sbuf, u32* scnt, int idx, float v) {
    u32 o = order_f32(v);
    u32 pos = atomicAdd(scnt, 1u);
    if (pos < LDSCAP)
        sbuf[pos] = ((u64)o << 32) | (u64)(0xFFFFFFFFu - (u32)idx);
}

__global__ __launch_bounds__(256) void collect_kernel(
    const float* __restrict__ logits,
    u32* __restrict__ gcnt,
    u64* __restrict__ gbuf)
{
    __shared__ u64 sbuf[LDSCAP];
    __shared__ u32 scnt;
    __shared__ u32 sbase;

    const int blk = blockIdx.x;
    const int b   = blk / BPB;          // const div -> magic mul
    const int c   = blk - b * BPB;
    const int t   = threadIdx.x;
    if (t == 0) scnt = 0;
    __syncthreads();

    const float4* __restrict__ L4 = (const float4*)(logits + (size_t)b * (NF4 * 4));
    const int base4 = c * CHUNK;

    // 8 independent loads in flight; invalid slots filled with -inf
    float4 v[8];
    #pragma unroll
    for (int j = 0; j < 8; ++j) {
        const int idx = base4 + j * 256 + t;
        if (idx < NF4) v[j] = L4[idx];
        else           v[j] = make_float4(-1e30f, -1e30f, -1e30f, -1e30f);
    }
    #pragma unroll
    for (int j = 0; j < 8; ++j) {
        const int i4 = (base4 + j * 256 + t) * 4;
        if (v[j].x >= GTHR) lpush(sbuf, &scnt, i4 + 0, v[j].x);
        if (v[j].y >= GTHR) lpush(sbuf, &scnt, i4 + 1, v[j].y);
        if (v[j].z >= GTHR) lpush(sbuf, &scnt, i4 + 2, v[j].z);
        if (v[j].w >= GTHR) lpush(sbuf, &scnt, i4 + 3, v[j].w);
    }
    __syncthreads();

    const u32 cnt = scnt;
    if (t == 0) {
        if (cnt > LDSCAP)   // LDS overflow (adversarial data): force fallback
            sbase = atomicAdd(&gcnt[b], 1000000u);
        else if (cnt > 0)
            sbase = atomicAdd(&gcnt[b], cnt);
        else
            sbase = 0;
    }
    __syncthreads();
    if (cnt > LDSCAP) return;           // dropped entries; fallback will recompute

    const u32 base = sbase;
    u64* __restrict__ gb = gbuf + (size_t)b * CAP;
    for (u32 i = t; i < cnt; i += 256)
        if (base + i < CAP) gb[base + i] = sbuf[i];
}

// ---------------- kernel B: per-batch select / rank / write ----------------

// suffix-scan hist counts -> exclusive-suffix starts (into hist AND cur),
// *s_B = max bucket with suffix(>=bk) >= K_TOP. Caller barriers before/after.
__device__ __forceinline__ void scan_and_find_B(u32* hist, u32* cur,
                                                u32* csum, u32* csum2,
                                                int* s_B, int t) {
    csum[t] = hist[4*t] + hist[4*t+1] + hist[4*t+2] + hist[4*t+3];
    __syncthreads();
    if (t < 64) {
        u32 s = 0;
        for (int u = 0; u < 16; ++u) s += csum[16*t + u];
        csum2[t] = s;
    }
    __syncthreads();
    if (t == 0) {     // exclusive suffix over the 64 supergroup sums
        u32 run = 0;
        for (int s = 63; s >= 0; --s) { u32 v = csum2[s]; csum2[s] = run; run += v; }
    }
    __syncthreads();
    {
        u32 ex = csum2[t >> 4];
        for (int g2 = (t | 15); g2 > t; --g2) ex += csum[g2];
        u32 h0 = hist[4*t], h1 = hist[4*t+1], h2 = hist[4*t+2], h3 = hist[4*t+3];
        u32 st3 = ex;
        u32 st2 = st3 + h3;
        u32 st1 = st2 + h2;
        u32 st0 = st1 + h1;
        int bl = -1;   // suffix(>=bk) non-increasing: first hit from top is max
        if      (st3 + h3 >= K_TOP) bl = 4*t + 3;
        else if (st2 + h2 >= K_TOP) bl = 4*t + 2;
        else if (st1 + h1 >= K_TOP) bl = 4*t + 1;
        else if (st0 + h0 >= K_TOP) bl = 4*t + 0;
        if (bl >= 0) atomicMax(s_B, bl);
        hist[4*t] = st0; hist[4*t+1] = st1; hist[4*t+2] = st2; hist[4*t+3] = st3;
        cur [4*t] = st0; cur [4*t+1] = st1; cur [4*t+2] = st2; cur [4*t+3] = st3;
    }
}

__device__ __forceinline__ void write_row(float* __restrict__ out, int b, int rank,
                                          u64 key, const float4* __restrict__ BX,
                                          float sx, float sy) {
    u32 o   = (u32)(key >> 32);
    u32 idx = ~((u32)key);
    float logit = unorder_f32(o);
    float score = 1.0f / (1.0f + expf(-logit));
    int label = (int)(idx % NCLS);
    int q     = (int)(idx / NCLS);
    float4 bx = BX[q];
    float* po = out + ((size_t)b * K_TOP + rank) * 6;
    po[0] = (float)label;
    po[1] = score;
    po[2] = (bx.x - 0.5f * bx.z) * sx;
    po[3] = (bx.y - 0.5f * bx.w) * sy;
    po[4] = bx.z * sx;
    po[5] = bx.w * sy;
}

// rank within own bucket segment (cand bucket-grouped); write top-300
__device__ __forceinline__ void rank_and_write(const u64* cand, const u32* hist,
                                               const u32* cur, u32 B, int t, int b,
                                               const float4* BX, float sx, float sy,
                                               float* out) {
    int total = (int)cur[B]; if (total > CAP) total = CAP;
    for (int i = t; i < total; i += 1024) {
        u64 key = cand[i];
        int bk   = (int)(key >> 52);
        int segS = (int)hist[bk];
        int segE = (int)cur[bk]; if (segE > CAP) segE = CAP;
        int r = segS;
        for (int j = segS; j < segE; ++j)
            r += (cand[j] > key) ? 1 : 0;
        if (r < K_TOP)
            write_row(out, b, r, key, BX, sx, sy);
    }
}

// fallback collect (bucket-filtered, cursor-scattered)
__device__ __forceinline__ void collect1(u32 o, int idx, u32 B,
                                         u64* cand, u32* cur) {
    u32 bk = o >> 20;
    if (bk >= B) {
        u32 pos = atomicAdd(&cur[bk], 1u);
        if (pos < CAP)
            cand[pos] = ((u64)o << 32) | (u64)(0xFFFFFFFFu - (u32)idx);
    }
}

__global__ __launch_bounds__(1024) void select_kernel(
    const float* __restrict__ logits,
    const float* __restrict__ boxes,
    const int*   __restrict__ osz,
    const u32*   __restrict__ gcnt,
    const u64*   __restrict__ gbuf,
    float*       __restrict__ out,
    int use_ws)
{
    __shared__ u32 hist[NBUCK];    // counts -> segment starts
    __shared__ u32 cur[NBUCK];     // fill cursors (ends after scatter)
    __shared__ u64 cand[CAP];      // bucket-grouped candidates (32 KB)
    __shared__ u32 csum[1024];
    __shared__ u32 csum2[64];
    __shared__ int s_B;

    const int b = blockIdx.x;
    const int t = threadIdx.x;
    const float4* L4 = (const float4*)(logits + (size_t)b * (NF4 * 4));
    const u64* gb = gbuf + (size_t)b * CAP;

    for (int i = t; i < NBUCK; i += 1024) hist[i] = 0;
    if (t == 0) s_B = -1;
    __syncthreads();

    const u32 BUCKET_G = order_f32(GTHR) >> 20;
    const int rawcnt = use_ws ? (int)gcnt[b] : -1;
    bool fast = use_ws && (rawcnt >= K_TOP) && (rawcnt <= CAP);

    const float sx = (float)osz[1];   // scale = [W, H, W, H]
    const float sy = (float)osz[0];
    const float4* BX = (const float4*)(boxes + (size_t)b * 4000);

    if (fast) {
        // histogram ONLY candidates; suffix counts exact for bk > BUCKET_G
        for (int i = t; i < rawcnt; i += 1024)
            atomicAdd(&hist[(u32)(gb[i] >> 52)], 1u);
        __syncthreads();
        scan_and_find_B(hist, cur, csum, csum2, &s_B, t);
        __syncthreads();
        fast = (s_B > (int)BUCKET_G);   // B valid only if above collect bucket
    }

    if (fast) {
        const u32 B = (u32)s_B;
        for (int i = t; i < rawcnt; i += 1024) {   // scatter bucket-grouped
            u64 k = gb[i];
            u32 pos = atomicAdd(&cur[(u32)(k >> 52)], 1u);
            if (pos < CAP) cand[pos] = k;
        }
        __syncthreads();
        rank_and_write(cand, hist, cur, B, t, b, BX, sx, sy, out);
    } else {
        // ---- fallback (degenerate data / no ws): full two-pass, always correct ----
        __syncthreads();
        for (int i = t; i < NBUCK; i += 1024) hist[i] = 0;
        if (t == 0) s_B = -1;
        __syncthreads();
        for (int i = t; i < NF4; i += 1024) {
            float4 v = L4[i];
            atomicAdd(&hist[order_f32(v.x) >> 20], 1u);
            atomicAdd(&hist[order_f32(v.y) >> 20], 1u);
            atomicAdd(&hist[order_f32(v.z) >> 20], 1u);
            atomicAdd(&hist[order_f32(v.w) >> 20], 1u);
        }
        __syncthreads();
        scan_and_find_B(hist, cur, csum, csum2, &s_B, t);
        __syncthreads();
        const u32 B = (u32)s_B;
        for (int i = t; i < NF4; i += 1024) {
            float4 v = L4[i];
            collect1(order_f32(v.x), 4*i + 0, B, cand, cur);
            collect1(order_f32(v.y), 4*i + 1, B, cand, cur);
            collect1(order_f32(v.z), 4*i + 2, B, cand, cur);
            collect1(order_f32(v.w), 4*i + 3, B, cand, cur);
        }
        __syncthreads();
        rank_and_write(cand, hist, cur, B, t, b, BX, sx, sy, out);
    }
}

extern "C" void kernel_launch(void* const* d_in, const int* in_sizes, int n_in,
                              void* d_out, int out_size, void* d_ws, size_t ws_size,
                              hipStream_t stream) {
    const float* logits = (const float*)d_in[0];
    const float* boxes  = (const float*)d_in[1];
    const int*   osz    = (const int*)d_in[2];
    float* out = (float*)d_out;

    const size_t need = 4096 + (size_t)NB * CAP * sizeof(u64);
    const int use_ws = (ws_size >= need) ? 1 : 0;
    u32* gcnt = (u32*)d_ws;
    u64* gbuf = (u64*)((char*)d_ws + 4096);

    if (use_ws) {
        hipMemsetAsync(d_ws, 0, NB * sizeof(u32), stream);
        collect_kernel<<<dim3(NB * BPB), dim3(256), 0, stream>>>(logits, gcnt, gbuf);
    }
    select_kernel<<<dim3(NB), dim3(1024), 0, stream>>>(logits, boxes, osz,
                                                       gcnt, gbuf, out, use_ws);
}

// Round 8
// 41.279 us; speedup vs baseline: 26.1869x; 1.2119x over previous
//
#include <hip/hip_runtime.h>

#define K_TOP  300
#define NCLS   80
#define NB     256
#define NF4    20000     // float4 per batch (80000 floats)
#define GTHR   2.2f      // static collect threshold; rank-300 sits at z~2.67
#define BPB    10        // collect blocks (chunks) per batch
#define CHUNK  2048      // float4 per chunk (last chunk ragged: 1568)
#define CAPC   256       // per-chunk candidate capacity (expect ~114 +/- 11)
#define NCAND  (BPB*CAPC)// 2560 per batch
#define NBK    1024      // select-phase bucket count
#define BIAS   3072u     // order_f32(GTHR)>>20 : lowest candidate bucket (fast path)

typedef unsigned int       u32;
typedef unsigned long long u64;

__device__ __forceinline__ u32 order_f32(float f) {
    u32 u = __float_as_uint(f);
    return u ^ ((u >> 31) ? 0xFFFFFFFFu : 0x80000000u);
}
__device__ __forceinline__ float unorder_f32(u32 u) {
    u32 v = (u & 0x80000000u) ? (u ^ 0x80000000u) : ~u;
    return __uint_as_float(v);
}

// ---------------- kernel A: chunked threshold-collect, private segments ----------------
__device__ __forceinline__ void lpush(u64* sbuf, u32* scnt, int idx, float v) {
    u32 o = order_f32(v);
    u32 pos = atomicAdd(scnt, 1u);
    if (pos < CAPC)
        sbuf[pos] = ((u64)o << 32) | (u64)(0xFFFFFFFFu - (u32)idx);
}

__global__ __launch_bounds__(256) void collect_kernel(
    const float* __restrict__ logits,
    u32* __restrict__ gcnt,
    u64* __restrict__ gbuf)
{
    __shared__ u64 sbuf[CAPC];
    __shared__ u32 scnt;

    const int blk = blockIdx.x;
    const int b   = blk / BPB;          // const div -> magic mul
    const int c   = blk - b * BPB;
    const int t   = threadIdx.x;
    if (t == 0) scnt = 0;
    __syncthreads();

    const float4* __restrict__ L4 = (const float4*)(logits + (size_t)b * (NF4 * 4));
    const int base4 = c * CHUNK;

    // 8 independent loads in flight; invalid slots filled with -inf
    float4 v[8];
    #pragma unroll
    for (int j = 0; j < 8; ++j) {
        const int idx = base4 + j * 256 + t;
        if (idx < NF4) v[j] = L4[idx];
        else           v[j] = make_float4(-1e30f, -1e30f, -1e30f, -1e30f);
    }
    #pragma unroll
    for (int j = 0; j < 8; ++j) {
        const int i4 = (base4 + j * 256 + t) * 4;
        if (v[j].x >= GTHR) lpush(sbuf, &scnt, i4 + 0, v[j].x);
        if (v[j].y >= GTHR) lpush(sbuf, &scnt, i4 + 1, v[j].y);
        if (v[j].z >= GTHR) lpush(sbuf, &scnt, i4 + 2, v[j].z);
        if (v[j].w >= GTHR) lpush(sbuf, &scnt, i4 + 3, v[j].w);
    }
    __syncthreads();

    const u32 cnt = scnt;
    u64* __restrict__ gb = gbuf + (size_t)blk * CAPC;   // private segment
    if (cnt <= CAPC) {
        if (t < (int)cnt) gb[t] = sbuf[t];              // coalesced, one store/thread
        if (t == 0) gcnt[blk] = cnt;                    // plain store, no atomic
    } else {
        if (t == 0) gcnt[blk] = 0xFFFFFFFFu;            // overflow sentinel -> fallback
    }
}

// ---------------- kernel B: per-batch select / rank / write ----------------

__device__ __forceinline__ void write_row(float* __restrict__ out, int b, int rank,
                                          u64 key, const float4* __restrict__ BX,
                                          float sx, float sy) {
    u32 o   = (u32)(key >> 32);
    u32 idx = ~((u32)key);
    float logit = unorder_f32(o);
    float score = 1.0f / (1.0f + expf(-logit));
    int label = (int)(idx % NCLS);
    int q     = (int)(idx / NCLS);
    float4 bx = BX[q];
    float* po = out + ((size_t)b * K_TOP + rank) * 6;
    po[0] = (float)label;
    po[1] = score;
    po[2] = (bx.x - 0.5f * bx.z) * sx;
    po[3] = (bx.y - 0.5f * bx.w) * sy;
    po[4] = bx.z * sx;
    po[5] = bx.w * sy;
}

// exclusive-suffix scan over NBK=1024 bucket counts in hist[]; on return
// hist[bk]=cur[bk]=start (suffix of buckets > bk), *s_B = max bk with
// start+count >= K_TOP. Caller barriers before/after.
__device__ __forceinline__ void scan1024(u32* hist, u32* cur, u32* csum2,
                                         int* s_B, int t) {
    if (t < 64) {
        u32 s = 0;
        for (int u = 0; u < 16; ++u) s += hist[16*t + u];
        csum2[t] = s;
    }
    __syncthreads();
    if (t == 0) {   // exclusive suffix over 64 supergroup sums
        u32 run = 0;
        for (int s = 63; s >= 0; --s) { u32 v = csum2[s]; csum2[s] = run; run += v; }
    }
    __syncthreads();
    u32 ex = csum2[t >> 4];
    for (int g = (t | 15); g > t; --g) ex += hist[g];
    u32 h = hist[t];
    if (ex + h >= K_TOP) atomicMax(s_B, t);
    __syncthreads();              // all reads of hist done
    hist[t] = ex;                 // segment start
    cur[t]  = ex;                 // fill cursor
}

// rank within own bucket segment (cand bucket-grouped); write top-300.
// bucket(key) = (key >> (32+shift)) - bias
__device__ __forceinline__ void rank_and_write(const u64* cand, const u32* hist,
                                               const u32* cur, u32 B, int shift, u32 bias,
                                               int t, int b, const float4* BX,
                                               float sx, float sy, float* out) {
    int total = (int)cur[B]; if (total > NCAND) total = NCAND;
    for (int i = t; i < total; i += 1024) {
        u64 key = cand[i];
        u32 bk   = (u32)(key >> (32 + shift)) - bias;
        int segS = (int)hist[bk];
        int segE = (int)cur[bk]; if (segE > NCAND) segE = NCAND;
        int r = segS;
        for (int j = segS; j < segE; ++j)
            r += (cand[j] > key) ? 1 : 0;
        if (r < K_TOP)
            write_row(out, b, r, key, BX, sx, sy);
    }
}

__global__ __launch_bounds__(1024) void select_kernel(
    const float* __restrict__ logits,
    const float* __restrict__ boxes,
    const int*   __restrict__ osz,
    const u32*   __restrict__ gcnt,
    const u64*   __restrict__ gbuf,
    float*       __restrict__ out,
    int use_ws)
{
    __shared__ u32 hist[NBK];     // counts -> segment starts
    __shared__ u32 cur[NBK];      // fill cursors (ends after scatter)
    __shared__ u64 cand[NCAND];   // bucket-grouped candidates (20 KB)
    __shared__ u32 csum2[64];
    __shared__ u32 s_cnt[BPB];
    __shared__ int s_B;

    const int b = blockIdx.x;
    const int t = threadIdx.x;
    const u64* __restrict__ gb = gbuf + (size_t)b * NCAND;

    if (t < BPB && use_ws) s_cnt[t] = gcnt[b * BPB + t];
    if (t == 0) s_B = -1;
    hist[t] = 0;   // t spans exactly NBK
    cur[t]  = 0;
    __syncthreads();

    bool fast = (use_ws != 0);
    int total = 0;
    if (fast) {
        #pragma unroll
        for (int c = 0; c < BPB; ++c) {
            u32 cc = s_cnt[c];
            if (cc > CAPC) { fast = false; break; }
            total += (int)cc;
        }
        fast = fast && (total >= K_TOP);   // total <= NCAND by construction
    }

    const float sx = (float)osz[1];   // scale = [W, H, W, H]
    const float sy = (float)osz[0];
    const float4* BX = (const float4*)(boxes + (size_t)b * 4000);

    if (fast) {
        // histogram candidates into 1024 biased buckets (all candidates >= BIAS)
        for (int i = t; i < NCAND; i += 1024) {
            int c = i >> 8, j = i & (CAPC - 1);
            if (j < (int)s_cnt[c])
                atomicAdd(&hist[(u32)(gb[i] >> 52) - BIAS], 1u);
        }
        __syncthreads();
        scan1024(hist, cur, csum2, &s_B, t);
        __syncthreads();
        fast = (s_B >= 1);   // B must be above GTHR's (partial) bucket
    }

    if (fast) {
        const u32 B = (u32)s_B;
        for (int i = t; i < NCAND; i += 1024) {    // scatter bucket-grouped
            int c = i >> 8, j = i & (CAPC - 1);
            if (j < (int)s_cnt[c]) {
                u64 k = gb[i];
                u32 pos = atomicAdd(&cur[(u32)(k >> 52) - BIAS], 1u);
                cand[pos] = k;   // pos < total <= NCAND guaranteed
            }
        }
        __syncthreads();
        rank_and_write(cand, hist, cur, B, 20, BIAS, t, b, BX, sx, sy, out);
    } else {
        // ---- fallback (degenerate data / no ws): two-pass, 10-bit buckets ----
        __syncthreads();
        hist[t] = 0; cur[t] = 0;
        if (t == 0) s_B = -1;
        __syncthreads();
        const float4* L4 = (const float4*)(logits + (size_t)b * (NF4 * 4));
        for (int i = t; i < NF4; i += 1024) {
            float4 v = L4[i];
            atomicAdd(&hist[order_f32(v.x) >> 22], 1u);
            atomicAdd(&hist[order_f32(v.y) >> 22], 1u);
            atomicAdd(&hist[order_f32(v.z) >> 22], 1u);
            atomicAdd(&hist[order_f32(v.w) >> 22], 1u);
        }
        __syncthreads();
        scan1024(hist, cur, csum2, &s_B, t);
        __syncthreads();
        const u32 B = (u32)s_B;
        for (int i = t; i < NF4; i += 1024) {
            float4 v = L4[i];
            float vv[4] = {v.x, v.y, v.z, v.w};
            #pragma unroll
            for (int u = 0; u < 4; ++u) {
                u32 o = order_f32(vv[u]);
                u32 bk = o >> 22;
                if (bk >= B) {
                    u32 pos = atomicAdd(&cur[bk], 1u);
                    if (pos < NCAND)
                        cand[pos] = ((u64)o << 32) |
                                    (u64)(0xFFFFFFFFu - (u32)(4*i + u));
                }
            }
        }
        __syncthreads();
        rank_and_write(cand, hist, cur, B, 22, 0u, t, b, BX, sx, sy, out);
    }
}

extern "C" void kernel_launch(void* const* d_in, const int* in_sizes, int n_in,
                              void* d_out, int out_size, void* d_ws, size_t ws_size,
                              hipStream_t stream) {
    const float* logits = (const float*)d_in[0];
    const float* boxes  = (const float*)d_in[1];
    const int*   osz    = (const int*)d_in[2];
    float* out = (float*)d_out;

    const size_t need = 16384 + (size_t)NB * NCAND * sizeof(u64);
    const int use_ws = (ws_size >= need) ? 1 : 0;
    u32* gcnt = (u32*)d_ws;                      // NB*BPB u32 = 10 KB
    u64* gbuf = (u64*)((char*)d_ws + 16384);

    if (use_ws)
        collect_kernel<<<dim3(NB * BPB), dim3(256), 0, stream>>>(logits, gcnt, gbuf);
    select_kernel<<<dim3(NB), dim3(1024), 0, stream>>>(logits, boxes, osz,
                                                       gcnt, gbuf, out, use_ws);
}